// Round 1
// baseline (982.454 us; speedup 1.0000x reference)
//
#include <hip/hip_runtime.h>
#include <hip/hip_bf16.h>
#include <math.h>

// Problem constants (from reference)
#define NN 10000      // nodes
#define NE 160000     // edges
#define ND 288        // edge feature dim
#define NS 32         // scalar channels (MUL)
#define HD 32         // head dim
#define NA 64         // node attr dim
#define EPB 5         // edges per chunk in node kernel (320 threads = 5 waves)

// ws layout (floats then ints), total ~87.1 MB:
//  T   [64*64*32] : T[i][j][c] = sum_d Wq2[i,c*32+d]*Wk2[j,c*32+d]
//  U   [64*32]    : U[j][c]    = sum_d bq2[c*32+d]*Wk2[j,c*32+d]
//  V   [64*32]    : V[i][c]    = sum_d Wq2[i,c*32+d]*bk2[c*32+d]
//  w   [32]       : w[c]       = sum_d bq2[c*32+d]*bk2[c*32+d]
//  Hq  [NN*64]    : per-node Q-MLP hidden (after 2 silu layers)
//  M   [NN*2080]  : per node: M[j*32+c] (2048) then bK[c] (32)
//  cnt[NN], cur[NN], offs[NN+1], sorted[NE]

__device__ __forceinline__ float silu_f(float x){ return x / (1.0f + __expf(-x)); }

__global__ void k_hist(const int* __restrict__ ec, int* __restrict__ cnt){
    int e = blockIdx.x*256 + threadIdx.x;
    if (e < NE) atomicAdd(&cnt[ec[e]], 1);
}

__global__ void k_scan(const int* __restrict__ cnt, int* __restrict__ offs){
    __shared__ int part[1024];
    int tid = threadIdx.x;
    int base = tid*10;
    int s = 0;
    #pragma unroll
    for (int i=0;i<10;i++){ int idx=base+i; s += (idx<NN)? cnt[idx] : 0; }
    part[tid] = s;
    __syncthreads();
    for (int off=1; off<1024; off<<=1){
        int v = (tid>=off)? part[tid-off] : 0;
        __syncthreads();
        part[tid] += v;
        __syncthreads();
    }
    int run = part[tid] - s;   // exclusive prefix of this thread's chunk
    for (int i=0;i<10;i++){ int idx=base+i; if(idx<NN){ offs[idx]=run; run += cnt[idx]; } }
    if (tid==1023) offs[NN] = part[1023];
}

__global__ void k_scatter(const int* __restrict__ ec, const int* __restrict__ offs,
                          int* __restrict__ cur, int* __restrict__ sorted){
    int e = blockIdx.x*256 + threadIdx.x;
    if (e < NE){
        int n = ec[e];
        int p = offs[n] + atomicAdd(&cur[n], 1);
        sorted[p] = e;
    }
}

__global__ void k_T(const float* __restrict__ Wq2, const float* __restrict__ Wk2,
                    float* __restrict__ T){
    int idx = blockIdx.x*256 + threadIdx.x;   // 131072 total; idx = i*2048 + j*32 + c
    int c = idx & 31, j = (idx>>5) & 63, i = idx >> 11;
    const float* a = Wq2 + i*1024 + c*32;
    const float* b = Wk2 + j*1024 + c*32;
    float s = 0.f;
    #pragma unroll
    for (int d=0; d<32; d++) s += a[d]*b[d];
    T[idx] = s;
}

__global__ void k_T2(const float* __restrict__ Wq2, const float* __restrict__ Wk2,
                     const float* __restrict__ bq2, const float* __restrict__ bk2,
                     float* __restrict__ U, float* __restrict__ V, float* __restrict__ w){
    int idx = blockIdx.x*256 + threadIdx.x;
    if (idx < 2048){
        int j = idx>>5, c = idx&31; float s=0.f;
        #pragma unroll
        for (int d=0; d<32; d++) s += bq2[c*32+d]*Wk2[j*1024 + c*32 + d];
        U[idx] = s;
    } else if (idx < 4096){
        int t = idx-2048; int i = t>>5, c = t&31; float s=0.f;
        #pragma unroll
        for (int d=0; d<32; d++) s += Wq2[i*1024 + c*32 + d]*bk2[c*32+d];
        V[t] = s;
    } else if (idx < 4128){
        int c = idx-4096; float s=0.f;
        #pragma unroll
        for (int d=0; d<32; d++) s += bq2[c*32+d]*bk2[c*32+d];
        w[c] = s;
    }
}

// per-node Q-MLP hidden: Hq[n] = silu(silu(attrs@Wq0+bq0)@Wq1+bq1), 4 nodes/block
__global__ __launch_bounds__(256) void k_H(const float* __restrict__ na,
                    const float* __restrict__ Wq0, const float* __restrict__ bq0,
                    const float* __restrict__ Wq1, const float* __restrict__ bq1,
                    float* __restrict__ Hq){
    __shared__ float W0s[4096], W1s[4096];
    __shared__ float as[4][64], h1s[4][64];
    int tid = threadIdx.x;
    for (int i=tid; i<4096; i+=256){ W0s[i]=Wq0[i]; W1s[i]=Wq1[i]; }
    int sg = tid>>6, lane = tid&63;
    int n = blockIdx.x*4 + sg;
    if (n < NN) as[sg][lane] = na[(size_t)n*64 + lane];
    __syncthreads();
    float h1 = 0.f;
    if (n < NN){
        float s = bq0[lane];
        #pragma unroll
        for (int i=0;i<64;i++) s += as[sg][i]*W0s[i*64+lane];
        h1 = silu_f(s);
        h1s[sg][lane] = h1;
    }
    __syncthreads();
    if (n < NN){
        float s = bq1[lane];
        #pragma unroll
        for (int i=0;i<64;i++) s += h1s[sg][i]*W1s[i*64+lane];
        Hq[(size_t)n*64 + lane] = silu_f(s);
    }
}

// M[n][j][c] = sum_i Hq[n,i]*T[i,j,c] + U[j,c];  bK[n][c] = sum_i Hq[n,i]*V[i,c] + w[c]
__global__ __launch_bounds__(256) void k_M(const float* __restrict__ Hq, const float* __restrict__ T,
                    const float* __restrict__ U, const float* __restrict__ V,
                    const float* __restrict__ w, float* __restrict__ M){
    __shared__ float hs[8][64];
    int tid = threadIdx.x;
    int nb = blockIdx.x*8;
    for (int i=tid; i<512; i+=256){
        int nn = i>>6, l = i&63; int n = nb+nn;
        hs[nn][l] = (n<NN) ? Hq[(size_t)n*64 + l] : 0.f;
    }
    __syncthreads();
    for (int k=0;k<8;k++){
        int jc = tid + k*256;
        float acc[8];
        #pragma unroll
        for (int nn=0;nn<8;nn++) acc[nn]=0.f;
        for (int i=0;i<64;i++){
            float tv = T[i*2048 + jc];
            #pragma unroll
            for (int nn=0;nn<8;nn++) acc[nn] += hs[nn][i]*tv;
        }
        float uv = U[jc];
        #pragma unroll
        for (int nn=0;nn<8;nn++){
            int n = nb+nn;
            if (n<NN) M[(size_t)n*2080 + jc] = acc[nn] + uv;
        }
    }
    if (tid < 32){
        int c = tid;
        for (int nn=0;nn<8;nn++){
            int n = nb+nn;
            if (n<NN){
                float s = w[c];
                #pragma unroll
                for (int i=0;i<64;i++) s += hs[nn][i]*V[i*32+c];
                M[(size_t)n*2080 + 2048 + c] = s;
            }
        }
    }
}

// One block per node: K-MLP per edge, logits via M, online segment softmax,
// irreps-weighted accumulation. 320 threads = 5 wave64.
__global__ __launch_bounds__(320) void k_node(
        const float* __restrict__ ef, const float* __restrict__ Mg,
        const float* __restrict__ Wk0, const float* __restrict__ bk0,
        const float* __restrict__ Wk1, const float* __restrict__ bk1,
        const int* __restrict__ offs, const int* __restrict__ sorted,
        float* __restrict__ out){
    __shared__ float W0s[2048];   // Wk0 [32][64]
    __shared__ float W1s[4096];   // Wk1 [64][64]
    __shared__ float Ms[2048];    // M[n] [j][c]
    __shared__ float bKs[32];
    __shared__ float xs[EPB][32];
    __shared__ float h1s[EPB][64];
    __shared__ float h2s[EPB][64];
    __shared__ float Ls[EPB][32];
    __shared__ float ps[EPB][32];
    __shared__ float msh[32], zsh[32], rsh[32];
    __shared__ float oacc[288];
    __shared__ int   es[EPB];

    int tid = threadIdx.x;
    int n   = blockIdx.x;
    int o0 = offs[n], o1 = offs[n+1];
    int count = o1 - o0;
    const float* Mn = Mg + (size_t)n*2080;

    for (int i=tid; i<2048; i+=320) W0s[i] = Wk0[i];
    for (int i=tid; i<4096; i+=320) W1s[i] = Wk1[i];
    for (int i=tid; i<2048; i+=320) Ms[i]  = Mn[i];
    if (tid < 32){ bKs[tid] = Mn[2048+tid]; msh[tid] = -INFINITY; zsh[tid] = 0.f; }
    if (tid < 288) oacc[tid] = 0.f;
    __syncthreads();

    int sg = tid>>6, lane = tid&63;
    int chcol = 0;  // channel for output column tid
    if (tid < 32)       chcol = tid;
    else if (tid < 128) chcol = (tid-32)/3;
    else if (tid < 288) chcol = (tid-128)/5;

    for (int base=0; base<count; base+=EPB){
        int ne = min(EPB, count-base);
        if (tid < ne) es[tid] = sorted[o0+base+tid];
        __syncthreads();
        if (sg < ne && lane < 32) xs[sg][lane] = ef[(size_t)es[sg]*ND + lane];
        __syncthreads();
        if (sg < ne){
            float s = bk0[lane];
            #pragma unroll
            for (int i=0;i<32;i++) s += xs[sg][i]*W0s[i*64+lane];
            h1s[sg][lane] = silu_f(s);
        }
        __syncthreads();
        if (sg < ne){
            float s = bk1[lane];
            #pragma unroll
            for (int i=0;i<64;i++) s += h1s[sg][i]*W1s[i*64+lane];
            h2s[sg][lane] = silu_f(s);
        }
        __syncthreads();
        if (sg < ne && lane < 32){
            int c = lane;
            float s = bKs[c];
            #pragma unroll
            for (int j=0;j<64;j++) s += h2s[sg][j]*Ms[j*32+c];
            Ls[sg][c] = 5.0f*s;
        }
        __syncthreads();
        if (tid < 32){
            int c = tid;
            float mold = msh[c], lmax = mold;
            for (int k=0;k<ne;k++) lmax = fmaxf(lmax, Ls[k][c]);
            float rr = __expf(mold - lmax);   // 0 on first chunk (mold=-inf)
            float zz = zsh[c]*rr;
            for (int k=0;k<ne;k++){ float pp = __expf(Ls[k][c]-lmax); ps[k][c]=pp; zz += pp; }
            zsh[c]=zz; msh[c]=lmax; rsh[c]=rr;
        }
        __syncthreads();
        if (tid < 288){
            float acc = oacc[tid]*rsh[chcol];
            for (int k=0;k<ne;k++) acc += ps[k][chcol]*ef[(size_t)es[k]*ND + tid];
            oacc[tid] = acc;
        }
        __syncthreads();
    }
    if (tid < 288){
        out[(size_t)n*ND + tid] = (count>0) ? oacc[tid]/zsh[chcol] : 0.f;
    }
}

extern "C" void kernel_launch(void* const* d_in, const int* in_sizes, int n_in,
                              void* d_out, int out_size, void* d_ws, size_t ws_size,
                              hipStream_t stream) {
    const float* edge_feat  = (const float*)d_in[0];
    const float* node_attrs = (const float*)d_in[1];
    const int*   edge_center= (const int*)  d_in[2];
    const float* Wq0 = (const float*)d_in[3];  const float* bq0 = (const float*)d_in[4];
    const float* Wq1 = (const float*)d_in[5];  const float* bq1 = (const float*)d_in[6];
    const float* Wq2 = (const float*)d_in[7];  const float* bq2 = (const float*)d_in[8];
    const float* Wk0 = (const float*)d_in[9];  const float* bk0 = (const float*)d_in[10];
    const float* Wk1 = (const float*)d_in[11]; const float* bk1 = (const float*)d_in[12];
    const float* Wk2 = (const float*)d_in[13]; const float* bk2 = (const float*)d_in[14];
    float* out = (float*)d_out;

    float* T   = (float*)d_ws;                 // 131072
    float* U   = T + 131072;                   // 2048
    float* V   = U + 2048;                     // 2048
    float* w   = V + 2048;                     // 32
    float* Hq  = w + 32;                       // 640000
    float* M   = Hq + (size_t)NN*64;           // 20,800,000
    int*   cnt = (int*)(M + (size_t)NN*2080);  // 10000
    int*   cur = cnt + NN;                     // 10000
    int*   offs= cur + NN;                     // 10001
    int*   sorted = offs + NN + 1;             // 160000

    // zero counters (cnt + cur are contiguous)
    hipMemsetAsync(cnt, 0, 2*NN*sizeof(int), stream);

    k_hist   <<<(NE+255)/256, 256, 0, stream>>>(edge_center, cnt);
    k_scan   <<<1, 1024, 0, stream>>>(cnt, offs);
    k_scatter<<<(NE+255)/256, 256, 0, stream>>>(edge_center, offs, cur, sorted);
    k_T      <<<512, 256, 0, stream>>>(Wq2, Wk2, T);
    k_T2     <<<17, 256, 0, stream>>>(Wq2, Wk2, bq2, bk2, U, V, w);
    k_H      <<<(NN+3)/4, 256, 0, stream>>>(node_attrs, Wq0, bq0, Wq1, bq1, Hq);
    k_M      <<<(NN+7)/8, 256, 0, stream>>>(Hq, T, U, V, w, M);
    k_node   <<<NN, 320, 0, stream>>>(edge_feat, M, Wk0, bk0, Wk1, bk1, offs, sorted, out);
}